// Round 1
// baseline (645.345 us; speedup 1.0000x reference)
//
#include <hip/hip_runtime.h>
#include <math.h>

// Problem constants
#define BN 4
#define NNODE 100
#define TT 20
#define HH 64
#define OO 128
#define M (BN*NNODE*NNODE)   // 40000 edges

// Workspace layout (float offsets)
#define WS_A1   0                      // A1[k][co], 3*64
#define WS_C3   192                    // c_t0[64], c_full[64], c_tL[64]
#define WS_W2T  384                    // w2 transposed: [(ci*3+k)*64+co], 12288
#define WS_EFA  (384 + 12288)          // efa[M*64] = 2,560,000
#define WS_ESC  (WS_EFA + M*64)        // scores -> exp(scores - max) [M]
#define WS_DEN  (WS_ESC + M)           // denom[4]
// total = 2,612,676 floats ~= 10.45 MB (fits standard workspace)

// ---------------------------------------------------------------------------
// Kernel A: fold edge-embedding + conv1 into rank-1 constants; transpose w2.
// ---------------------------------------------------------------------------
__global__ void prep_kernel(const float* __restrict__ W_edge,
                            const float* __restrict__ b_edge,
                            const float* __restrict__ w1,
                            const float* __restrict__ b1,
                            const float* __restrict__ w2,
                            float* __restrict__ ws)
{
    int tid = threadIdx.x; // 256 threads, 1 block
    if (tid < 64) {
        int co = tid;
        float a[3] = {0.f, 0.f, 0.f};
        float bk[3] = {0.f, 0.f, 0.f};
        for (int ci = 0; ci < HH; ++ci) {
            float we = W_edge[ci], be = b_edge[ci];
#pragma unroll
            for (int k = 0; k < 3; ++k) {
                float w = w1[(co*HH + ci)*3 + k];
                a[k]  = fmaf(we, w, a[k]);
                bk[k] = fmaf(be, w, bk[k]);
            }
        }
        float bb = b1[co];
        ws[WS_A1 + 0*64 + co] = a[0];
        ws[WS_A1 + 1*64 + co] = a[1];
        ws[WS_A1 + 2*64 + co] = a[2];
        ws[WS_C3 +        co] = bb + bk[1] + bk[2];          // t == 0 (k=0 padded out)
        ws[WS_C3 +  64 +  co] = bb + bk[0] + bk[1] + bk[2];  // interior t
        ws[WS_C3 + 128 +  co] = bb + bk[0] + bk[1];          // t == T-1 (k=2 padded out)
    }
    // transpose conv2_w [co][ci][k] -> w2t[(ci*3+k)*64+co] for lane-coalesced reads
    for (int s = tid; s < HH*HH*3; s += blockDim.x) {
        int k  = s % 3;
        int ci = (s/3) % HH;
        int co = s / (3*HH);
        ws[WS_W2T + (ci*3 + k)*64 + co] = w2[s];
    }
}

// ---------------------------------------------------------------------------
// Kernel B: one wave (64 lanes) per edge. lane = output channel co.
// conv1(rank-1) -> conv2 -> temporal attention -> efa + spatial score.
// ---------------------------------------------------------------------------
__launch_bounds__(64)
__global__ void edge_kernel(const float* __restrict__ ew_g,
                            const float* __restrict__ ws_c,
                            const float* __restrict__ b2,
                            const float* __restrict__ Wt1,
                            const float* __restrict__ bt1,
                            const float* __restrict__ Wt2,
                            const float* __restrict__ bt2,
                            const float* __restrict__ Ws1,
                            const float* __restrict__ bs1,
                            const float* __restrict__ Ws2,
                            const float* __restrict__ bs2,
                            float* __restrict__ efa_g,
                            float* __restrict__ score_g)
{
    __shared__ float ewp[24];        // padded ew: [0]=0, [1..20]=ew, [21]=0
    __shared__ float ybuf[22*64];    // y1 padded rows [t=0..21][ci]; reused for y2

    const int m  = blockIdx.x;
    const int co = threadIdx.x;      // 0..63

    // stage padded edge-weight vector
    if (co < TT)       ewp[co+1] = ew_g[m*TT + co];
    else if (co == TT) { ewp[0] = 0.f; ewp[21] = 0.f; }

    // fused conv1 constants (coalesced)
    const float a0 = ws_c[WS_A1 +       co];
    const float a1 = ws_c[WS_A1 +  64 + co];
    const float a2 = ws_c[WS_A1 + 128 + co];
    const float c0 = ws_c[WS_C3 +       co];
    const float cf = ws_c[WS_C3 +  64 + co];
    const float cL = ws_c[WS_C3 + 128 + co];

    __syncthreads();

    // ---- conv1 (3 MACs per (t,co)) + relu -> LDS (padded rows 0 and 21 zero)
    ybuf[co] = 0.f;
    ybuf[21*64 + co] = 0.f;
#pragma unroll
    for (int t = 0; t < TT; ++t) {
        float c = (t == 0) ? c0 : (t == TT-1) ? cL : cf;
        float v = fmaf(a0, ewp[t], fmaf(a1, ewp[t+1], fmaf(a2, ewp[t+2], c)));
        ybuf[(t+1)*64 + co] = fmaxf(v, 0.f);
    }
    __syncthreads();

    // ---- conv2: acc[t][co] = b2[co] + sum_ci sum_k w2[co,ci,k]*y1[t+k-1][ci]
    float acc[TT];
    {
        const float bb2 = b2[co];
#pragma unroll
        for (int t = 0; t < TT; ++t) acc[t] = bb2;
        const float* __restrict__ w2t = ws_c + WS_W2T;
        for (int ci = 0; ci < HH; ++ci) {
            float w0 = w2t[(ci*3 + 0)*64 + co];
            float w1v = w2t[(ci*3 + 1)*64 + co];
            float w2v = w2t[(ci*3 + 2)*64 + co];
            float col[TT+2];
#pragma unroll
            for (int t = 0; t < TT+2; ++t) col[t] = ybuf[t*64 + ci];  // LDS broadcast
#pragma unroll
            for (int t = 0; t < TT; ++t)
                acc[t] = fmaf(w0, col[t], fmaf(w1v, col[t+1], fmaf(w2v, col[t+2], acc[t])));
        }
    }
    __syncthreads();   // everyone done reading y1 before overwrite

    // relu, stash y2 into LDS rows 0..19 (xc in the reference)
#pragma unroll
    for (int t = 0; t < TT; ++t) {
        acc[t] = fmaxf(acc[t], 0.f);
        ybuf[t*64 + co] = acc[t];
    }
    __syncthreads();

    // ---- temporal attention: u = tanh(y2 @ Wt1 + bt1); s = u @ Wt2 + bt2
    float u[TT];
    {
        const float bt1c = bt1[co];
#pragma unroll
        for (int t = 0; t < TT; ++t) u[t] = bt1c;
        for (int ci = 0; ci < HH; ++ci) {
            float w = Wt1[ci*64 + co];
#pragma unroll
            for (int t = 0; t < TT; ++t)
                u[t] = fmaf(w, ybuf[t*64 + ci], u[t]);
        }
    }
    float s[TT];
    {
        const float wt2c = Wt2[co];
#pragma unroll
        for (int t = 0; t < TT; ++t) {
            float v = tanhf(u[t]) * wt2c;
#pragma unroll
            for (int off = 32; off >= 1; off >>= 1)
                v += __shfl_xor(v, off, 64);
            s[t] = v;   // identical across lanes after butterfly
        }
    }
    // softmax over T (all lanes redundantly)
    {
        const float bt2v = bt2[0];
        float mx = -1e30f;
#pragma unroll
        for (int t = 0; t < TT; ++t) { s[t] += bt2v; mx = fmaxf(mx, s[t]); }
        float sum = 0.f;
#pragma unroll
        for (int t = 0; t < TT; ++t) { s[t] = __expf(s[t] - mx); sum += s[t]; }
        float inv = 1.f / sum;
#pragma unroll
        for (int t = 0; t < TT; ++t) s[t] *= inv;
    }
    // efa[co] = sum_t y2[t][co] * att[t]   (y2 still live in acc regs)
    float efa = 0.f;
#pragma unroll
    for (int t = 0; t < TT; ++t) efa = fmaf(acc[t], s[t], efa);
    efa_g[m*64 + co] = efa;

    // ---- spatial score for this edge
    float us = bs1[co];
    for (int ci = 0; ci < HH; ++ci) {
        float e = __shfl(efa, ci, 64);
        us = fmaf(e, Ws1[ci*64 + co], us);
    }
    float v = tanhf(us) * Ws2[co];
#pragma unroll
    for (int off = 32; off >= 1; off >>= 1)
        v += __shfl_xor(v, off, 64);
    if (co == 0) score_g[m] = v + bs2[0];
}

// ---------------------------------------------------------------------------
// Kernel C: per-batch softmax stats over the 10,000 edge scores.
// Converts scores in-place to exp(s - max); writes per-batch denom.
// ---------------------------------------------------------------------------
__global__ void spatial_softmax_kernel(float* __restrict__ score_g,
                                       float* __restrict__ den_g)
{
    const int b = blockIdx.x;        // 4 blocks
    const int tid = threadIdx.x;     // 256
    __shared__ float red[256];
    float mx = -1e30f;
    for (int i = tid; i < NNODE*NNODE; i += 256)
        mx = fmaxf(mx, score_g[b*NNODE*NNODE + i]);
    red[tid] = mx; __syncthreads();
    for (int w = 128; w >= 1; w >>= 1) {
        if (tid < w) red[tid] = fmaxf(red[tid], red[tid + w]);
        __syncthreads();
    }
    mx = red[0]; __syncthreads();
    float sum = 0.f;
    for (int i = tid; i < NNODE*NNODE; i += 256) {
        float e = __expf(score_g[b*NNODE*NNODE + i] - mx);
        score_g[b*NNODE*NNODE + i] = e;
        sum += e;
    }
    red[tid] = sum; __syncthreads();
    for (int w = 128; w >= 1; w >>= 1) {
        if (tid < w) red[tid] += red[tid + w];
        __syncthreads();
    }
    if (tid == 0) den_g[b] = red[0];
}

// ---------------------------------------------------------------------------
// Kernel D: node aggregation + 3-layer MLP. One wave per (b, i) node.
// ---------------------------------------------------------------------------
__launch_bounds__(64)
__global__ void node_kernel(const float* __restrict__ efa_g,
                            const float* __restrict__ e_g,
                            const float* __restrict__ den_g,
                            const float* __restrict__ Wg1,
                            const float* __restrict__ bg1,
                            const float* __restrict__ Wg2,
                            const float* __restrict__ bg2,
                            const float* __restrict__ Wout,
                            const float* __restrict__ bout,
                            float* __restrict__ out)
{
    const int bi = blockIdx.x;       // b*100 + i, 400 blocks
    const int b  = bi / NNODE;
    const int co = threadIdx.x;      // 0..63
    const float invden = 1.f / den_g[b];

    const int base = bi * NNODE;     // edge m = bi*100 + j
    float accv = 0.f;
    for (int j = 0; j < NNODE; ++j) {
        float e = e_g[base + j];                       // broadcast
        accv = fmaf(e, efa_g[(base + j)*64 + co], accv); // coalesced
    }
    float node = accv * invden;

    float g1 = bg1[co];
    for (int ci = 0; ci < HH; ++ci)
        g1 = fmaf(__shfl(node, ci, 64), Wg1[ci*64 + co], g1);
    g1 = fmaxf(g1, 0.f);

    float g2 = bg2[co];
    for (int ci = 0; ci < HH; ++ci)
        g2 = fmaf(__shfl(g1, ci, 64), Wg2[ci*64 + co], g2);
    g2 = fmaxf(g2, 0.f);

    float o0 = bout[co], o1 = bout[co + 64];
    for (int ci = 0; ci < HH; ++ci) {
        float g = __shfl(g2, ci, 64);
        o0 = fmaf(g, Wout[ci*OO + co], o0);
        o1 = fmaf(g, Wout[ci*OO + co + 64], o1);
    }
    out[bi*OO + co]      = fmaxf(o0, 0.f);
    out[bi*OO + co + 64] = fmaxf(o1, 0.f);
}

// ---------------------------------------------------------------------------
extern "C" void kernel_launch(void* const* d_in, const int* in_sizes, int n_in,
                              void* d_out, int out_size, void* d_ws, size_t ws_size,
                              hipStream_t stream)
{
    const float* ew      = (const float*)d_in[0];
    const float* W_edge  = (const float*)d_in[1];
    const float* b_edge  = (const float*)d_in[2];
    const float* conv1_w = (const float*)d_in[3];
    const float* conv1_b = (const float*)d_in[4];
    const float* conv2_w = (const float*)d_in[5];
    const float* conv2_b = (const float*)d_in[6];
    const float* Wt1     = (const float*)d_in[7];
    const float* bt1     = (const float*)d_in[8];
    const float* Wt2     = (const float*)d_in[9];
    const float* bt2     = (const float*)d_in[10];
    const float* Ws1     = (const float*)d_in[11];
    const float* bs1     = (const float*)d_in[12];
    const float* Ws2     = (const float*)d_in[13];
    const float* bs2     = (const float*)d_in[14];
    const float* Wg1     = (const float*)d_in[15];
    const float* bg1     = (const float*)d_in[16];
    const float* Wg2     = (const float*)d_in[17];
    const float* bg2     = (const float*)d_in[18];
    const float* Wout    = (const float*)d_in[19];
    const float* bout    = (const float*)d_in[20];

    float* ws  = (float*)d_ws;
    float* out = (float*)d_out;

    prep_kernel<<<1, 256, 0, stream>>>(W_edge, b_edge, conv1_w, conv1_b, conv2_w, ws);

    edge_kernel<<<M, 64, 0, stream>>>(ew, ws, conv2_b,
                                      Wt1, bt1, Wt2, bt2,
                                      Ws1, bs1, Ws2, bs2,
                                      ws + WS_EFA, ws + WS_ESC);

    spatial_softmax_kernel<<<BN, 256, 0, stream>>>(ws + WS_ESC, ws + WS_DEN);

    node_kernel<<<BN*NNODE, 64, 0, stream>>>(ws + WS_EFA, ws + WS_ESC, ws + WS_DEN,
                                             Wg1, bg1, Wg2, bg2, Wout, bout, out);
}

// Round 2
// 281.826 us; speedup vs baseline: 2.2899x; 2.2899x over previous
//
#include <hip/hip_runtime.h>
#include <math.h>

// Problem constants
#define BN 4
#define NNODE 100
#define TT 20
#define HH 64
#define OO 128
#define M (BN*NNODE*NNODE)   // 40000 edges

// Workspace layout (float offsets)
#define WS_A1   0                       // A1[k][co], 3*64
#define WS_C3   192                     // c_t0[64], c_full[64], c_tL[64]
#define WS_W2F  384                     // w2 A-frags (f16): 24 frags * 512 halfs = 6144 floats
#define WS_WT1F (384 + 6144)            // Wt1 B-frags (f16): 8 frags * 512 halfs = 2048 floats
#define WS_EFA  (WS_WT1F + 2048)        // efa[M*64]
#define WS_ESC  (WS_EFA + M*64)         // scores -> exp(scores - max) [M]
#define WS_DEN  (WS_ESC + M)            // denom[4]

typedef _Float16 half8 __attribute__((ext_vector_type(8)));
typedef float float4v __attribute__((ext_vector_type(4)));

__device__ __forceinline__ float fast_tanh(float x) {
    float e = __expf(2.f * x);
    return 1.f - __fdividef(2.f, e + 1.f);
}

// ---------------------------------------------------------------------------
// Kernel A: fold edge-embedding + conv1 into rank-1 constants; pack MFMA frags.
// q-index for conv2 GEMM: q = k*64 + ci  (K = 192)
// A-frag (w2):  frag f = mt*6+kt, elem: co = mt*16+(lane&15), q = kt*32+(lane>>4)*8+j
// B-frag (Wt1): frag f = kt*4+nt, elem: ci = kt*32+(lane>>4)*8+j, co = nt*16+(lane&15)
// ---------------------------------------------------------------------------
__global__ void prep_kernel(const float* __restrict__ W_edge,
                            const float* __restrict__ b_edge,
                            const float* __restrict__ w1,
                            const float* __restrict__ b1,
                            const float* __restrict__ w2,
                            const float* __restrict__ Wt1,
                            float* __restrict__ ws)
{
    int tid = threadIdx.x; // 256 threads, 1 block
    if (tid < 64) {
        int co = tid;
        float a[3] = {0.f, 0.f, 0.f};
        float bk[3] = {0.f, 0.f, 0.f};
        for (int ci = 0; ci < HH; ++ci) {
            float we = W_edge[ci], be = b_edge[ci];
#pragma unroll
            for (int k = 0; k < 3; ++k) {
                float w = w1[(co*HH + ci)*3 + k];
                a[k]  = fmaf(we, w, a[k]);
                bk[k] = fmaf(be, w, bk[k]);
            }
        }
        float bb = b1[co];
        ws[WS_A1 + 0*64 + co] = a[0];
        ws[WS_A1 + 1*64 + co] = a[1];
        ws[WS_A1 + 2*64 + co] = a[2];
        ws[WS_C3 +        co] = bb + bk[1] + bk[2];          // t == 0
        ws[WS_C3 +  64 +  co] = bb + bk[0] + bk[1] + bk[2];  // interior
        ws[WS_C3 + 128 +  co] = bb + bk[0] + bk[1];          // t == T-1
    }
    _Float16* w2f  = (_Float16*)(ws + WS_W2F);
    _Float16* wt1f = (_Float16*)(ws + WS_WT1F);
    // w2 A-frags: 24*64*8 = 12288 elements
    for (int s = tid; s < 24*64*8; s += blockDim.x) {
        int j    = s & 7;
        int lane = (s >> 3) & 63;
        int f    = s >> 9;           // 0..23
        int mt = f / 6, kt = f % 6;
        int co = mt*16 + (lane & 15);
        int q  = kt*32 + ((lane >> 4) << 3) + j;
        int k  = q >> 6, ci = q & 63;
        w2f[f*512 + lane*8 + j] = (_Float16)w2[(co*HH + ci)*3 + k];
    }
    // Wt1 B-frags: 8*64*8 = 4096 elements
    for (int s = tid; s < 8*64*8; s += blockDim.x) {
        int j    = s & 7;
        int lane = (s >> 3) & 63;
        int f    = s >> 9;           // 0..7
        int kt = f / 4, nt = f % 4;
        int ci = kt*32 + ((lane >> 4) << 3) + j;
        int co = nt*16 + (lane & 15);
        wt1f[f*512 + lane*8 + j] = (_Float16)Wt1[ci*HH + co];
    }
}

// ---------------------------------------------------------------------------
// Kernel B: one wave per edge. conv1 (rank-1, fp32) -> conv2 (MFMA f16) ->
// temporal attention (MFMA f16 + fp32 softmax) -> efa + spatial score.
// ---------------------------------------------------------------------------
__launch_bounds__(64)
__global__ void edge_kernel(const float* __restrict__ ew_g,
                            const float* __restrict__ ws_c,
                            const float* __restrict__ b2,
                            const float* __restrict__ bt1,
                            const float* __restrict__ Wt2,
                            const float* __restrict__ bt2,
                            const float* __restrict__ Ws1,
                            const float* __restrict__ bs1,
                            const float* __restrict__ Ws2,
                            const float* __restrict__ bs2,
                            float* __restrict__ efa_g,
                            float* __restrict__ score_g)
{
    __shared__ _Float16 y1B[TT*192];   // [t][q], q = k*64+ci  (7680 B)
    __shared__ _Float16 y2L[TT*72];    // [t][ci], stride 72 halfs (2880 B)
    __shared__ float    sbuf[TT];
    __shared__ float    ewp[22];

    const int m    = blockIdx.x;
    const int lane = threadIdx.x;       // 0..63
    const int l15  = lane & 15;
    const int quad = lane >> 4;

    if (lane < TT) ewp[lane + 1] = ew_g[m*TT + lane];
    if (lane == 0) { ewp[0] = 0.f; ewp[21] = 0.f; }

    const float a0 = ws_c[WS_A1 +       lane];
    const float a1 = ws_c[WS_A1 +  64 + lane];
    const float a2 = ws_c[WS_A1 + 128 + lane];
    const float c0 = ws_c[WS_C3 +       lane];
    const float cf = ws_c[WS_C3 +  64 + lane];
    const float cL = ws_c[WS_C3 + 128 + lane];
    __syncthreads();

    // ---- conv1 (3 FMA per t) + relu; lane = channel ci here
    float y1v[TT];
#pragma unroll
    for (int t = 0; t < TT; ++t) {
        float c = (t == 0) ? c0 : (t == TT-1) ? cL : cf;
        y1v[t] = fmaxf(fmaf(a0, ewp[t], fmaf(a1, ewp[t+1], fmaf(a2, ewp[t+2], c))), 0.f);
    }
    // pack B for conv2: y1B[t][k*64+ci] = y1p[t+k-1][ci]
#pragma unroll
    for (int t = 0; t < TT; ++t) {
        y1B[t*192 +       lane] = (_Float16)((t >= 1)    ? y1v[t-1] : 0.f);
        y1B[t*192 +  64 + lane] = (_Float16)y1v[t];
        y1B[t*192 + 128 + lane] = (_Float16)((t < TT-1)  ? y1v[t+1] : 0.f);
    }
    __syncthreads();

    // ---- conv2 GEMM: D[co=64, t=20] = A[64,192] * B[192,20pad32], 48 MFMAs
    const _Float16* w2f = (const _Float16*)(ws_c + WS_W2F);
    float4v acc[4][2];
#pragma unroll
    for (int mt = 0; mt < 4; ++mt)
#pragma unroll
        for (int nt = 0; nt < 2; ++nt)
            acc[mt][nt] = float4v{0.f, 0.f, 0.f, 0.f};

    const int tB0 = l15;                                  // 0..15 (valid)
    const int tB1 = (16 + l15 < TT) ? (16 + l15) : TT-1;  // clamped; garbage cols ignored
#pragma unroll
    for (int kt = 0; kt < 6; ++kt) {
        half8 b0 = *(const half8*)&y1B[tB0*192 + kt*32 + quad*8];
        half8 b1 = *(const half8*)&y1B[tB1*192 + kt*32 + quad*8];
#pragma unroll
        for (int mt = 0; mt < 4; ++mt) {
            half8 a = *(const half8*)(w2f + ((mt*6 + kt)*64 + lane)*8);
            acc[mt][0] = __builtin_amdgcn_mfma_f32_16x16x32_f16(a, b0, acc[mt][0], 0, 0, 0);
            acc[mt][1] = __builtin_amdgcn_mfma_f32_16x16x32_f16(a, b1, acc[mt][1], 0, 0, 0);
        }
    }
    // bias + relu + store y2 (f16) to LDS [t][ci]
#pragma unroll
    for (int mt = 0; mt < 4; ++mt) {
#pragma unroll
        for (int reg = 0; reg < 4; ++reg) {
            int co = mt*16 + quad*4 + reg;
            float bb = b2[co];
            float v0 = fmaxf(acc[mt][0][reg] + bb, 0.f);
            y2L[l15*72 + co] = (_Float16)v0;              // t = l15
            if (l15 < 4) {
                float v1 = fmaxf(acc[mt][1][reg] + bb, 0.f);
                y2L[(16 + l15)*72 + co] = (_Float16)v1;   // t = 16+l15
            }
        }
    }
    __syncthreads();

    // ---- Wt1 GEMM: U[t=20, co=64] = y2[20,64] * Wt1[64,64], 16 MFMAs
    const _Float16* wt1f = (const _Float16*)(ws_c + WS_WT1F);
    float4v u[2][4];
#pragma unroll
    for (int mt = 0; mt < 2; ++mt)
#pragma unroll
        for (int nt = 0; nt < 4; ++nt)
            u[mt][nt] = float4v{0.f, 0.f, 0.f, 0.f};

    const int tA0 = l15;
    const int tA1 = (16 + l15 < TT) ? (16 + l15) : TT-1;  // clamped; garbage rows ignored
#pragma unroll
    for (int kt = 0; kt < 2; ++kt) {
        half8 af0 = *(const half8*)&y2L[tA0*72 + kt*32 + quad*8];
        half8 af1 = *(const half8*)&y2L[tA1*72 + kt*32 + quad*8];
#pragma unroll
        for (int nt = 0; nt < 4; ++nt) {
            half8 bf = *(const half8*)(wt1f + ((kt*4 + nt)*64 + lane)*8);
            u[0][nt] = __builtin_amdgcn_mfma_f32_16x16x32_f16(af0, bf, u[0][nt], 0, 0, 0);
            u[1][nt] = __builtin_amdgcn_mfma_f32_16x16x32_f16(af1, bf, u[1][nt], 0, 0, 0);
        }
    }

    // ---- temporal attention scores: s[t] = bt2 + sum_co tanh(u + bt1[co]) * Wt2[co]
    float bt1v[4], wt2v[4];
#pragma unroll
    for (int nt = 0; nt < 4; ++nt) {
        bt1v[nt] = bt1[nt*16 + l15];
        wt2v[nt] = Wt2[nt*16 + l15];
    }
#pragma unroll
    for (int mt = 0; mt < 2; ++mt) {
#pragma unroll
        for (int reg = 0; reg < 4; ++reg) {
            int t = mt*16 + quad*4 + reg;
            float p = 0.f;
#pragma unroll
            for (int nt = 0; nt < 4; ++nt)
                p += fast_tanh(u[mt][nt][reg] + bt1v[nt]) * wt2v[nt];
            // reduce across the 16 lanes of this quad (cols co)
            p += __shfl_xor(p, 1, 64);
            p += __shfl_xor(p, 2, 64);
            p += __shfl_xor(p, 4, 64);
            p += __shfl_xor(p, 8, 64);
            if (l15 == 0 && t < TT) sbuf[t] = p;
        }
    }
    __syncthreads();

    // ---- softmax over T (redundant per lane) + efa
    float att[TT];
    {
        const float bt2v = bt2[0];
        float mx = -1e30f;
#pragma unroll
        for (int t = 0; t < TT; ++t) { att[t] = sbuf[t] + bt2v; mx = fmaxf(mx, att[t]); }
        float sum = 0.f;
#pragma unroll
        for (int t = 0; t < TT; ++t) { att[t] = __expf(att[t] - mx); sum += att[t]; }
        float inv = __fdividef(1.f, sum);
#pragma unroll
        for (int t = 0; t < TT; ++t) att[t] *= inv;
    }
    float efa = 0.f;
#pragma unroll
    for (int t = 0; t < TT; ++t)
        efa = fmaf((float)y2L[t*72 + lane], att[t], efa);
    efa_g[m*64 + lane] = efa;

    // ---- spatial score for this edge (fp32)
    float us = bs1[lane];
    for (int ci = 0; ci < HH; ++ci)
        us = fmaf(__shfl(efa, ci, 64), Ws1[ci*HH + lane], us);
    float v = fast_tanh(us) * Ws2[lane];
#pragma unroll
    for (int off = 32; off >= 1; off >>= 1)
        v += __shfl_xor(v, off, 64);
    if (lane == 0) score_g[m] = v + bs2[0];
}

// ---------------------------------------------------------------------------
// Kernel C: per-batch softmax stats over the 10,000 edge scores.
// ---------------------------------------------------------------------------
__global__ void spatial_softmax_kernel(float* __restrict__ score_g,
                                       float* __restrict__ den_g)
{
    const int b = blockIdx.x;        // 4 blocks
    const int tid = threadIdx.x;     // 256
    __shared__ float red[256];
    float mx = -1e30f;
    for (int i = tid; i < NNODE*NNODE; i += 256)
        mx = fmaxf(mx, score_g[b*NNODE*NNODE + i]);
    red[tid] = mx; __syncthreads();
    for (int w = 128; w >= 1; w >>= 1) {
        if (tid < w) red[tid] = fmaxf(red[tid], red[tid + w]);
        __syncthreads();
    }
    mx = red[0]; __syncthreads();
    float sum = 0.f;
    for (int i = tid; i < NNODE*NNODE; i += 256) {
        float e = __expf(score_g[b*NNODE*NNODE + i] - mx);
        score_g[b*NNODE*NNODE + i] = e;
        sum += e;
    }
    red[tid] = sum; __syncthreads();
    for (int w = 128; w >= 1; w >>= 1) {
        if (tid < w) red[tid] += red[tid + w];
        __syncthreads();
    }
    if (tid == 0) den_g[b] = red[0];
}

// ---------------------------------------------------------------------------
// Kernel D: node aggregation + 3-layer MLP. One wave per (b, i) node.
// ---------------------------------------------------------------------------
__launch_bounds__(64)
__global__ void node_kernel(const float* __restrict__ efa_g,
                            const float* __restrict__ e_g,
                            const float* __restrict__ den_g,
                            const float* __restrict__ Wg1,
                            const float* __restrict__ bg1,
                            const float* __restrict__ Wg2,
                            const float* __restrict__ bg2,
                            const float* __restrict__ Wout,
                            const float* __restrict__ bout,
                            float* __restrict__ out)
{
    const int bi = blockIdx.x;       // b*100 + i
    const int b  = bi / NNODE;
    const int co = threadIdx.x;      // 0..63
    const float invden = __fdividef(1.f, den_g[b]);

    const int base = bi * NNODE;     // edge m = bi*100 + j
    float accv = 0.f;
    for (int j = 0; j < NNODE; ++j) {
        float e = e_g[base + j];
        accv = fmaf(e, efa_g[(base + j)*64 + co], accv);
    }
    float node = accv * invden;

    float g1 = bg1[co];
    for (int ci = 0; ci < HH; ++ci)
        g1 = fmaf(__shfl(node, ci, 64), Wg1[ci*HH + co], g1);
    g1 = fmaxf(g1, 0.f);

    float g2 = bg2[co];
    for (int ci = 0; ci < HH; ++ci)
        g2 = fmaf(__shfl(g1, ci, 64), Wg2[ci*HH + co], g2);
    g2 = fmaxf(g2, 0.f);

    float o0 = bout[co], o1 = bout[co + 64];
    for (int ci = 0; ci < HH; ++ci) {
        float g = __shfl(g2, ci, 64);
        o0 = fmaf(g, Wout[ci*OO + co], o0);
        o1 = fmaf(g, Wout[ci*OO + co + 64], o1);
    }
    out[bi*OO + co]      = fmaxf(o0, 0.f);
    out[bi*OO + co + 64] = fmaxf(o1, 0.f);
}

// ---------------------------------------------------------------------------
extern "C" void kernel_launch(void* const* d_in, const int* in_sizes, int n_in,
                              void* d_out, int out_size, void* d_ws, size_t ws_size,
                              hipStream_t stream)
{
    const float* ew      = (const float*)d_in[0];
    const float* W_edge  = (const float*)d_in[1];
    const float* b_edge  = (const float*)d_in[2];
    const float* conv1_w = (const float*)d_in[3];
    const float* conv1_b = (const float*)d_in[4];
    const float* conv2_w = (const float*)d_in[5];
    const float* conv2_b = (const float*)d_in[6];
    const float* Wt1     = (const float*)d_in[7];
    const float* bt1     = (const float*)d_in[8];
    const float* Wt2     = (const float*)d_in[9];
    const float* bt2     = (const float*)d_in[10];
    const float* Ws1     = (const float*)d_in[11];
    const float* bs1     = (const float*)d_in[12];
    const float* Ws2     = (const float*)d_in[13];
    const float* bs2     = (const float*)d_in[14];
    const float* Wg1     = (const float*)d_in[15];
    const float* bg1     = (const float*)d_in[16];
    const float* Wg2     = (const float*)d_in[17];
    const float* bg2     = (const float*)d_in[18];
    const float* Wout    = (const float*)d_in[19];
    const float* bout    = (const float*)d_in[20];

    float* ws  = (float*)d_ws;
    float* out = (float*)d_out;

    prep_kernel<<<1, 256, 0, stream>>>(W_edge, b_edge, conv1_w, conv1_b, conv2_w, Wt1, ws);

    edge_kernel<<<M, 64, 0, stream>>>(ew, ws, conv2_b,
                                      bt1, Wt2, bt2,
                                      Ws1, bs1, Ws2, bs2,
                                      ws + WS_EFA, ws + WS_ESC);

    spatial_softmax_kernel<<<BN, 256, 0, stream>>>(ws + WS_ESC, ws + WS_DEN);

    node_kernel<<<BN*NNODE, 64, 0, stream>>>(ws + WS_EFA, ws + WS_ESC, ws + WS_DEN,
                                             Wg1, bg1, Wg2, bg2, Wout, bout, out);
}